// Round 6
// baseline (220.170 us; speedup 1.0000x reference)
//
#include <hip/hip_runtime.h>

namespace {

constexpr int OUT_F = 11008;
constexpr int IN_F  = 4096;
constexpr int NF4   = IN_F / 4;       // 1024 float4 per batch row
constexpr int NLOAD = IN_F / (64 * 4); // 16 dwordx4 loads per row per wave

typedef int   int4v   __attribute__((ext_vector_type(4)));
typedef float float4v __attribute__((ext_vector_type(4)));

__global__ __launch_bounds__(256, 2) void qlinear_kernel(
    const float* __restrict__ x,       // [4, IN_F]
    const int*   __restrict__ qw,      // [OUT_F, IN_F] int8 values in int32
    const float* __restrict__ scales,  // [OUT_F]
    const float* __restrict__ bias,    // [OUT_F]
    float*       __restrict__ out,     // [4, OUT_F]
    unsigned*    __restrict__ ticket)  // [1], zeroed before launch
{
    // x staged once per persistent block: 64 KB fp32 (exact).
    __shared__ float4v xs[4 * NF4];

    const int tid = threadIdx.x;
    const float4v* xg = (const float4v*)x;
#pragma unroll
    for (int j = 0; j < (4 * NF4) / 256; ++j)
        xs[j * 256 + tid] = xg[j * 256 + tid];
    __syncthreads();

    const int lane = tid & 63;
    const int4v* qw4 = (const int4v*)qw;   // [OUT_F * 1024]

    // Per-wave: grab a row ticket (lane 0), broadcast.
    auto grab = [&]() -> int {
        int t = 0;
        if (lane == 0) t = (int)atomicAdd(ticket, 1u);
        return __shfl(t, 0, 64);
    };

    int4v buf0[NLOAD], buf1[NLOAD];

    auto issue = [&](int4v (&buf)[NLOAD], int row) {
        const int4v* wp = qw4 + (size_t)row * (NF4 / 4) * 4;  // row * 1024
#pragma unroll
        for (int i = 0; i < NLOAD; ++i)
            buf[i] = wp[i * 64 + lane];
    };

    auto compute_store = [&](int4v (&buf)[NLOAD], int row) {
        float acc[4] = {0.f, 0.f, 0.f, 0.f};
#pragma unroll
        for (int k = 0; k < NLOAD; ++k) {
            float4v xv[4];
#pragma unroll
            for (int b = 0; b < 4; ++b)
                xv[b] = xs[b * (NF4 / 4) * 4 + k * 64 + lane];  // b*1024 + ...
            float4v wf;
            wf.x = (float)buf[k].x;
            wf.y = (float)buf[k].y;
            wf.z = (float)buf[k].z;
            wf.w = (float)buf[k].w;
#pragma unroll
            for (int b = 0; b < 4; ++b) {
                acc[b] += wf.x * xv[b].x;
                acc[b] += wf.y * xv[b].y;
                acc[b] += wf.z * xv[b].z;
                acc[b] += wf.w * xv[b].w;
            }
        }
        // Butterfly reduce across 64 lanes.
#pragma unroll
        for (int b = 0; b < 4; ++b) {
#pragma unroll
            for (int m = 32; m >= 1; m >>= 1)
                acc[b] += __shfl_xor(acc[b], m, 64);
        }
        if (lane == 0) {
            const float s  = scales[row];
            const float bz = bias[row];
#pragma unroll
            for (int b = 0; b < 4; ++b)
                out[(size_t)b * OUT_F + row] = acc[b] * s + bz;
        }
    };

    // 2-deep row pipeline: while computing one bank, the other's 16 KB is in
    // flight. Tickets decouple waves (no barriers after the x stage).
    int t_a = grab();
    if (t_a < OUT_F) issue(buf0, t_a);
    int t_b = grab();
    if (t_b < OUT_F) issue(buf1, t_b);

    for (;;) {
        if (t_a >= OUT_F) break;
        compute_store(buf0, t_a);
        t_a = grab();
        if (t_a < OUT_F) issue(buf0, t_a);

        if (t_b >= OUT_F) break;
        compute_store(buf1, t_b);
        t_b = grab();
        if (t_b < OUT_F) issue(buf1, t_b);
    }
    // Drain: exactly one bank may hold an issued-but-unprocessed row.
    if (t_b < OUT_F)      compute_store(buf1, t_b);  // broke on t_a
    else if (t_a < OUT_F) compute_store(buf0, t_a);  // broke on t_b
}

}  // namespace

extern "C" void kernel_launch(void* const* d_in, const int* in_sizes, int n_in,
                              void* d_out, int out_size, void* d_ws, size_t ws_size,
                              hipStream_t stream) {
    const float* x      = (const float*)d_in[0];
    const int*   qw     = (const int*)d_in[1];
    const float* scales = (const float*)d_in[2];
    const float* bias   = (const float*)d_in[3];
    float*       out    = (float*)d_out;
    unsigned*    ticket = (unsigned*)d_ws;

    hipMemsetAsync(ticket, 0, sizeof(unsigned), stream);

    // Persistent grid: 2 blocks/CU x 256 CUs.
    qlinear_kernel<<<512, 256, 0, stream>>>(x, qw, scales, bias, out, ticket);
}

// Round 7
// 136.764 us; speedup vs baseline: 1.6099x; 1.6099x over previous
//
#include <hip/hip_runtime.h>

namespace {

constexpr int OUT_F = 11008;
constexpr int IN_F  = 4096;
constexpr int R4    = IN_F / 4;        // 1024 x4-vectors per row (x and qw)
constexpr int NPAIR = OUT_F / 2;       // 5504 row-pairs
constexpr int NBLK  = 512;             // persistent: 2 blocks/CU x 256 CU
constexpr int NWAVE = NBLK * 4;        // 2048 waves
constexpr int K_STEPS = IN_F / (64 * 4); // 16 (one int4/lane/row/step)
constexpr int CHUNK  = 2;              // steps per pipeline slot
constexpr int NCHUNK = K_STEPS / CHUNK;  // 8
constexpr int DEPTH  = 4;              // NCHUNK % DEPTH == 0 -> static slots across pairs

typedef int   int4v   __attribute__((ext_vector_type(4)));
typedef float float4v __attribute__((ext_vector_type(4)));

__global__ __launch_bounds__(256, 2) void qlinear_kernel(
    const float* __restrict__ x,       // [4, IN_F]
    const int*   __restrict__ qw,      // [OUT_F, IN_F]
    const float* __restrict__ scales,  // [OUT_F]
    const float* __restrict__ bias,    // [OUT_F]
    float*       __restrict__ out)     // [4, OUT_F]
{
    __shared__ float4v xs[4 * R4];     // 64 KB fp32 (exact), staged ONCE per block

    const int tid  = threadIdx.x;
    const int lane = tid & 63;
    const int wid  = tid >> 6;
    const int wave_gid = blockIdx.x * 4 + wid;

    const int4v* qw4 = (const int4v*)qw;

    int4v w[DEPTH][2][CHUNK];          // 64 VGPR pipeline buffer

    // Issue first pair's 3-deep prologue BEFORE staging x: ~12 KB/wave of
    // weight loads overlap the LDS-stage bubble.
    const int p0 = wave_gid;           // < NPAIR always (2048 < 5504)
    {
        const int4v* a = qw4 + (size_t)(2 * p0) * R4;
        const int4v* b = a + R4;
#pragma unroll
        for (int pc = 0; pc < DEPTH - 1; ++pc)
#pragma unroll
            for (int s = 0; s < CHUNK; ++s) {
                w[pc][0][s] = a[(pc * CHUNK + s) * 64 + lane];
                w[pc][1][s] = b[(pc * CHUNK + s) * 64 + lane];
            }
    }

    // Stage x (issued after the weight prologue so its ds_write waits do not
    // force the weight loads to retire first -- they are older in the queue).
    const float4v* xg = (const float4v*)x;
#pragma unroll
    for (int j = 0; j < (4 * R4) / 256; ++j)       // 16 iters
        xs[j * 256 + tid] = xg[j * 256 + tid];
    __syncthreads();

    for (int p = p0; p < NPAIR; p += NWAVE) {
        const int4v* a = qw4 + (size_t)(2 * p) * R4;
        const int4v* b = a + R4;
        const int  pn       = p + NWAVE;
        const bool has_next = pn < NPAIR;
        const int4v* an = qw4 + (size_t)(2 * (has_next ? pn : p0)) * R4;
        const int4v* bn = an + R4;

        float acc[2][4];
#pragma unroll
        for (int r = 0; r < 2; ++r)
#pragma unroll
            for (int bt = 0; bt < 4; ++bt)
                acc[r][bt] = 0.0f;

#pragma unroll
        for (int c = 0; c < NCHUNK; ++c) {
            // Issue virtual chunk c+3: current pair while it lasts, then the
            // NEXT pair's prologue (slots line up: NCHUNK % DEPTH == 0).
            constexpr int D1 = DEPTH - 1;
            const int vi = c + D1;
            if (vi < NCHUNK) {
#pragma unroll
                for (int s = 0; s < CHUNK; ++s) {
                    w[vi % DEPTH][0][s] = a[(vi * CHUNK + s) * 64 + lane];
                    w[vi % DEPTH][1][s] = b[(vi * CHUNK + s) * 64 + lane];
                }
            } else if (has_next) {     // wave-uniform guard
                const int vj = vi - NCHUNK;      // 0..2, compile-time
#pragma unroll
                for (int s = 0; s < CHUNK; ++s) {
                    w[vj % DEPTH][0][s] = an[(vj * CHUNK + s) * 64 + lane];
                    w[vj % DEPTH][1][s] = bn[(vj * CHUNK + s) * 64 + lane];
                }
            }

            // Compute chunk c from slot c%DEPTH.
            const int cc = c % DEPTH;
#pragma unroll
            for (int s = 0; s < CHUNK; ++s) {
                const int k = c * CHUNK + s;
                float4v xv[4];
#pragma unroll
                for (int bt = 0; bt < 4; ++bt)
                    xv[bt] = xs[bt * (R4 / 4) * 4 + k * 64 + lane];  // bt*1024 + ...

#pragma unroll
                for (int r = 0; r < 2; ++r) {
                    float4v wf;
                    wf.x = (float)w[cc][r][s].x;
                    wf.y = (float)w[cc][r][s].y;
                    wf.z = (float)w[cc][r][s].z;
                    wf.w = (float)w[cc][r][s].w;
#pragma unroll
                    for (int bt = 0; bt < 4; ++bt) {
                        acc[r][bt] += wf.x * xv[bt].x;
                        acc[r][bt] += wf.y * xv[bt].y;
                        acc[r][bt] += wf.z * xv[bt].z;
                        acc[r][bt] += wf.w * xv[bt].w;
                    }
                }
            }
        }

        // Reduce across 64 lanes and store rows 2p, 2p+1.
#pragma unroll
        for (int r = 0; r < 2; ++r)
#pragma unroll
            for (int bt = 0; bt < 4; ++bt) {
                float v = acc[r][bt];
#pragma unroll
                for (int m = 32; m >= 1; m >>= 1)
                    v += __shfl_xor(v, m, 64);
                acc[r][bt] = v;
            }

        if (lane == 0) {
#pragma unroll
            for (int r = 0; r < 2; ++r) {
                const int row = 2 * p + r;
                const float sc = scales[row];
                const float bz = bias[row];
#pragma unroll
                for (int bt = 0; bt < 4; ++bt)
                    out[(size_t)bt * OUT_F + row] = acc[r][bt] * sc + bz;
            }
        }
    }
}

}  // namespace

extern "C" void kernel_launch(void* const* d_in, const int* in_sizes, int n_in,
                              void* d_out, int out_size, void* d_ws, size_t ws_size,
                              hipStream_t stream) {
    const float* x      = (const float*)d_in[0];
    const int*   qw     = (const int*)d_in[1];
    const float* scales = (const float*)d_in[2];
    const float* bias   = (const float*)d_in[3];
    float*       out    = (float*)d_out;

    qlinear_kernel<<<NBLK, 256, 0, stream>>>(x, qw, scales, bias, out);
}